// Round 8
// baseline (33.047 us; speedup 1.0000x reference)
//
#include <hip/hip_runtime.h>
#include <math.h>

// MACE equivariant score head — 2-kernel form.
// Dead code: Wss (d_in[5]), Wvv (d_in[7]) — s3=silu(s2) is deleted in the reference.
//
// out[n,m] = sum_c vraw[n,c,m] * h[n,c]
// h[n,c]   = sum_u z[n,u] * E[u,c]
//   z[n,u] = t[n]*wtld[u] + sum_q feat[n,q] * W~[q,u]     (W~[q,u] = W1s[16+q,u])
//   wtld[u]= sum_{p<16} Wt[p] * W1s[p,u]
//   E[u,c] = scale * sum_v D[u,v] * W1v[c,v],  D[u,v] = dot(Wsv[u,v,:], W2)
//   scale  = 1/(S*V*sqrt(V))   (all fan-in norms folded into E)
//
// K_A: block = u (144 blocks). Streams the contiguous 64KB slab Wsv[u,:,:],
//      computes D[u,:] in LDS, contracts with W1v -> E[u,:]. (Old K23's work
//      rides inside the D-producer: chain depth 3 -> 2.)
// K_B: 256 blocks x 16 rows. W~ + E staged in LDS (154.6 KB total), 4 rows
//      per wave register-blocked so each LDS sweep of W~/E serves 4 rows.

#define S 144
#define V 128

// ---------------- K_A: E[u,:] from Wsv slab u ----------------
__global__ __launch_bounds__(256) void kA_E(const float* __restrict__ Wsv,
                                            const float* __restrict__ W2,
                                            const float* __restrict__ W1v,
                                            float* __restrict__ E) {
    __shared__ float Dsh[V];
    __shared__ float Epart[2][V];
    const int tid = threadIdx.x;
    const int wave = tid >> 6;
    const int lane = tid & 63;
    const int half = lane >> 5;          // row within pair
    const int j = lane & 31;             // float4 index within 128-float row
    const int u = blockIdx.x;

    const float4* Wsv4 = (const float4*)Wsv;   // v-row stride = 32 float4
    const float4 w4 = ((const float4*)W2)[j];

    // D-phase: wave w covers v in [32w, 32w+32) as 16 row-pairs.
    const size_t base4 = ((size_t)u * V + 32 * wave) * 32;
    float4 a[16];
#pragma unroll
    for (int i = 0; i < 16; ++i)
        a[i] = Wsv4[base4 + (size_t)(2 * i + half) * 32 + j];

#pragma unroll
    for (int i = 0; i < 16; ++i) {
        float acc = a[i].x * w4.x + a[i].y * w4.y + a[i].z * w4.z + a[i].w * w4.w;
#pragma unroll
        for (int off = 1; off < 32; off <<= 1)
            acc += __shfl_xor(acc, off, 64);   // width-32: stays in half
        if (j == 0) Dsh[32 * wave + 2 * i + half] = acc;
    }
    __syncthreads();

    // E-phase: E[u,c] = scale * sum_v Dsh[v]*W1v[c,v]; thread (c, v-half)
    const int c = tid & 127, vh = tid >> 7;
    const float4* W1v4 = (const float4*)W1v;
    const float4* D4 = (const float4*)Dsh;
    float acc = 0.f;
#pragma unroll
    for (int i = 0; i < 16; ++i) {
        const float4 wv = W1v4[c * 32 + vh * 16 + i];
        const float4 dv = D4[vh * 16 + i];
        acc += wv.x * dv.x + wv.y * dv.y + wv.z * dv.z + wv.w * dv.w;
    }
    Epart[vh][c] = acc;
    __syncthreads();
    if (tid < V) {
        const float scale = 1.0f / (144.0f * 128.0f * sqrtf(128.0f));
        E[u * V + tid] = scale * (Epart[0][tid] + Epart[1][tid]);
    }
}

// ---------------- K_B: z-GEMV + h-GEMV + epilogue ----------------
// 256 blocks x 256 thr (4 waves), 16 rows/block, 4 rows/wave.
// LDS: Wq 72KB + Esh 72KB + wtld + ubuf (per-wave s-then-z overlay) = 154.6KB.
__global__ __launch_bounds__(256) void kB_main(const float* __restrict__ feat,
                                               const float* __restrict__ times,
                                               const float* __restrict__ Wt,
                                               const float* __restrict__ W1s,
                                               const float* __restrict__ Eg,
                                               float* __restrict__ out) {
    __shared__ float Wq[128 * S];     // Wq[q*144+u] = W1s[16+q, u]
    __shared__ float Esh[S * V];      // Esh[u*128+c]
    __shared__ float wtld[S];
    __shared__ float ubuf[4][640];    // per wave: srow [4][128] then zrow [4][144]

    const int tid = threadIdx.x;
    const int wave = tid >> 6;
    const int lane = tid & 63;
    const int n0 = blockIdx.x * 16 + wave * 4;

    // this wave's 4 rows: vector part -> regs (lane owns channels 2l, 2l+1)
    float2 va[4][3];
#pragma unroll
    for (int r = 0; r < 4; ++r) {
        const float* p = feat + (size_t)(n0 + r) * 512 + V + 6 * lane;
        va[r][0] = *(const float2*)(p + 0);
        va[r][1] = *(const float2*)(p + 2);
        va[r][2] = *(const float2*)(p + 4);
    }
    // scalar part -> ubuf (srow view)
#pragma unroll
    for (int r = 0; r < 4; ++r) {
        const float2 sv = *(const float2*)(feat + (size_t)(n0 + r) * 512 + 2 * lane);
        *(float2*)&ubuf[wave][r * 128 + 2 * lane] = sv;
    }
    float tval[4];
#pragma unroll
    for (int r = 0; r < 4; ++r) tval[r] = times[n0 + r];

    // stage E (coalesced float4: 4608 = 256*18)
    {
        const float4* src = (const float4*)Eg;
        float4* dst = (float4*)Esh;
#pragma unroll
        for (int k = 0; k < 18; ++k)
            dst[tid + 256 * k] = src[tid + 256 * k];
    }
    // stage W~: q = wave + 4k
#pragma unroll 4
    for (int k = 0; k < 32; ++k) {
        const int q = wave + 4 * k;
        const float* srcr = W1s + (size_t)(16 + q) * S;
        Wq[q * S + lane] = srcr[lane];
        Wq[q * S + 64 + lane] = srcr[64 + lane];
        if (lane < 16) Wq[q * S + 128 + lane] = srcr[128 + lane];
    }
    // wtld[u] = sum_{p<16} Wt[p]*W1s[p,u]
    if (tid < S) {
        float acc = 0.f;
#pragma unroll
        for (int p = 0; p < 16; ++p)
            acc = fmaf(Wt[p], W1s[p * S + tid], acc);
        wtld[tid] = acc;
    }
    __syncthreads();

    // ---- z-phase: z[r][u] for u = lane, 64+lane, 128+lane(<16) ----
    const float wt_a = wtld[lane];
    const float wt_b = wtld[64 + lane];
    const float wt_c = (lane < 16) ? wtld[128 + lane] : 0.f;
    float za[4], zb[4], zc[4];
#pragma unroll
    for (int r = 0; r < 4; ++r) {
        za[r] = tval[r] * wt_a;
        zb[r] = tval[r] * wt_b;
        zc[r] = tval[r] * wt_c;
    }
#pragma unroll 8
    for (int q = 0; q < 128; ++q) {
        const float wa = Wq[q * S + lane];
        const float wb = Wq[q * S + 64 + lane];
        const float wc = (lane < 16) ? Wq[q * S + 128 + lane] : 0.f;
#pragma unroll
        for (int r = 0; r < 4; ++r) {
            const float sq = ubuf[wave][r * 128 + q];   // broadcast
            za[r] = fmaf(sq, wa, za[r]);
            zb[r] = fmaf(sq, wb, zb[r]);
            zc[r] = fmaf(sq, wc, zc[r]);
        }
    }
    // overlay write: zrow view (all srow reads of THIS wave are complete;
    // DS ops from one wave execute in order, so no barrier needed)
#pragma unroll
    for (int r = 0; r < 4; ++r) {
        ubuf[wave][r * S + lane] = za[r];
        ubuf[wave][r * S + 64 + lane] = zb[r];
        if (lane < 16) ubuf[wave][r * S + 128 + lane] = zc[r];
    }

    // ---- h-phase: h[r][c=2l,2l+1] = sum_u z[r][u] * E[u,c] ----
    float h0[4] = {0.f, 0.f, 0.f, 0.f};
    float h1[4] = {0.f, 0.f, 0.f, 0.f};
#pragma unroll 4
    for (int u = 0; u < S; ++u) {
        const float2 m2 = *(const float2*)&Esh[u * V + 2 * lane];
#pragma unroll
        for (int r = 0; r < 4; ++r) {
            const float zu = ubuf[wave][r * S + u];     // broadcast
            h0[r] = fmaf(zu, m2.x, h0[r]);
            h1[r] = fmaf(zu, m2.y, h1[r]);
        }
    }

    // ---- epilogue: out[n,m] = sum_c vraw[c,m]*h[c] ----
    // lane l holds c=2l (va[0].x, va[0].y, va[1].x) and c=2l+1 (va[1].y, va[2].x, va[2].y)
#pragma unroll
    for (int r = 0; r < 4; ++r) {
        float pm0 = va[r][0].x * h0[r] + va[r][1].y * h1[r];
        float pm1 = va[r][0].y * h0[r] + va[r][2].x * h1[r];
        float pm2 = va[r][1].x * h0[r] + va[r][2].y * h1[r];
#pragma unroll
        for (int off = 1; off < 64; off <<= 1) {
            pm0 += __shfl_xor(pm0, off, 64);
            pm1 += __shfl_xor(pm1, off, 64);
            pm2 += __shfl_xor(pm2, off, 64);
        }
        if (lane == 0) {
            out[(n0 + r) * 3 + 0] = pm0;
            out[(n0 + r) * 3 + 1] = pm1;
            out[(n0 + r) * 3 + 2] = pm2;
        }
    }
}

extern "C" void kernel_launch(void* const* d_in, const int* in_sizes, int n_in,
                              void* d_out, int out_size, void* d_ws, size_t ws_size,
                              hipStream_t stream) {
    const float* feat  = (const float*)d_in[0];  // [4096, 512]
    const float* times = (const float*)d_in[1];  // [4096, 1]
    const float* Wt    = (const float*)d_in[2];  // [1,16]
    const float* W1s   = (const float*)d_in[3];  // [144,144]
    const float* W1v   = (const float*)d_in[4];  // [128,128]
    // d_in[5] = Wss  -- dead path
    const float* Wsv   = (const float*)d_in[6];  // [144,128,128]
    // d_in[7] = Wvv  -- dead path
    const float* W2    = (const float*)d_in[8];  // [128,1]

    float* E = (float*)d_ws;   // 18432 f32

    kA_E<<<dim3(144), dim3(256), 0, stream>>>(Wsv, W2, W1v, E);
    kB_main<<<dim3(256), dim3(256), 0, stream>>>(feat, times, Wt, W1s, E, (float*)d_out);
}

// Round 9
// 27.131 us; speedup vs baseline: 1.2180x; 1.2180x over previous
//
#include <hip/hip_runtime.h>
#include <math.h>

// MACE equivariant score head — 2-kernel form, v2 (z hoisted into K_A).
// Dead code: Wss (d_in[5]), Wvv (d_in[7]) — s3=silu(s2) is deleted in the reference.
//
// out[n,m] = sum_c vraw[n,c,m] * h[n,c],   h[n,c] = sum_u z[n,u] * E[u,c]
//   z[n,u] = t[n]*wtld[u] + sum_q feat[n,q] * W1s[16+q,u]   (raw, no scale)
//   wtld[u]= sum_{p<16} Wt[p] * W1s[p,u]
//   E[u,c] = scale * sum_v D[u,v] * W1v[c,v],  D[u,v] = dot(Wsv[u,v,:], W2)
//   scale  = 1/(S*V*sqrt(V))   (all fan-in norms folded into E)
//
// K_A: 400 blocks. [0,144): E-blocks (stream 64KB slab Wsv[u,:,:] -> D -> E[u,:]).
//      [144,400): Z-blocks (16 rows each) — independent of D/E, overlaps the
//      BW-bound E-stream with VALU work. All blocks co-resident (small LDS).
// K_B: 512 blocks x 8 rows. LDS = E 72KB + zbuf 4.5KB = 76.5KB -> 2 blocks/CU,
//      8 waves/CU. One GEMV h = z.E + register epilogue.

#define S 144
#define V 128

// ---------------- K_A ----------------
__global__ __launch_bounds__(256) void kA(const float* __restrict__ feat,
                                          const float* __restrict__ times,
                                          const float* __restrict__ Wt,
                                          const float* __restrict__ W1s,
                                          const float* __restrict__ W1v,
                                          const float* __restrict__ Wsv,
                                          const float* __restrict__ W2,
                                          float* __restrict__ E,
                                          float* __restrict__ Z) {
    __shared__ float Dsh[V];
    __shared__ float Epart[2][V];
    __shared__ float srow[16][V];   // Z-path (8 KB)
    __shared__ float wtld[S];       // Z-path

    const int tid = threadIdx.x;
    const int wave = tid >> 6;
    const int lane = tid & 63;

    if (blockIdx.x < S) {
        // ---- E-block: u = blockIdx.x ----
        const int half = lane >> 5;
        const int j = lane & 31;
        const int u = blockIdx.x;
        const float4* Wsv4 = (const float4*)Wsv;
        const float4 w4 = ((const float4*)W2)[j];
        const size_t base4 = ((size_t)u * V + 32 * wave) * 32;
        float4 a[16];
#pragma unroll
        for (int i = 0; i < 16; ++i)
            a[i] = Wsv4[base4 + (size_t)(2 * i + half) * 32 + j];
#pragma unroll
        for (int i = 0; i < 16; ++i) {
            float acc = a[i].x * w4.x + a[i].y * w4.y + a[i].z * w4.z + a[i].w * w4.w;
#pragma unroll
            for (int off = 1; off < 32; off <<= 1)
                acc += __shfl_xor(acc, off, 64);    // width-32: stays in half
            if (j == 0) Dsh[32 * wave + 2 * i + half] = acc;
        }
        __syncthreads();
        // E[u,c] = scale * sum_v Dsh[v]*W1v[c,v]; thread = (c, v-half)
        const int c = tid & 127, vh = tid >> 7;
        const float4* W1v4 = (const float4*)W1v;
        const float4* D4 = (const float4*)Dsh;
        float acc = 0.f;
#pragma unroll
        for (int i = 0; i < 16; ++i) {
            const float4 wv = W1v4[c * 32 + vh * 16 + i];
            const float4 dv = D4[vh * 16 + i];
            acc += wv.x * dv.x + wv.y * dv.y + wv.z * dv.z + wv.w * dv.w;
        }
        Epart[vh][c] = acc;
        __syncthreads();
        if (tid < V) {
            const float scale = 1.0f / (144.0f * 128.0f * sqrtf(128.0f));
            E[u * V + tid] = scale * (Epart[0][tid] + Epart[1][tid]);
        }
    } else {
        // ---- Z-block: 16 rows ----
        const int n0 = (blockIdx.x - S) * 16;
        // stage scalar rows (wave w: rows 4w..4w+3), coalesced float2
#pragma unroll
        for (int r = 0; r < 4; ++r) {
            const int row = wave * 4 + r;
            const float2 sv = *(const float2*)(feat + (size_t)(n0 + row) * 512 + 2 * lane);
            *(float2*)&srow[row][2 * lane] = sv;
        }
        if (tid < S) {
            float acc = 0.f;
#pragma unroll
            for (int p = 0; p < 16; ++p)
                acc = fmaf(Wt[p], W1s[p * S + tid], acc);
            wtld[tid] = acc;
        }
        __syncthreads();

        const float wt_a = wtld[lane];
        const float wt_b = wtld[64 + lane];
        const float wt_c = (lane < 16) ? wtld[128 + lane] : 0.f;
        float tv[4];
#pragma unroll
        for (int r = 0; r < 4; ++r) tv[r] = times[n0 + wave * 4 + r];
        float za[4], zb[4], zc[4];
#pragma unroll
        for (int r = 0; r < 4; ++r) {
            za[r] = tv[r] * wt_a;
            zb[r] = tv[r] * wt_b;
            zc[r] = tv[r] * wt_c;
        }
#pragma unroll 4
        for (int q = 0; q < 128; ++q) {
            const float* wr = W1s + (size_t)(16 + q) * S;
            const float wa = wr[lane];
            const float wb = wr[64 + lane];
            const float wc = (lane < 16) ? wr[128 + lane] : 0.f;
#pragma unroll
            for (int r = 0; r < 4; ++r) {
                const float sq = srow[wave * 4 + r][q];   // LDS broadcast
                za[r] = fmaf(sq, wa, za[r]);
                zb[r] = fmaf(sq, wb, zb[r]);
                zc[r] = fmaf(sq, wc, zc[r]);
            }
        }
#pragma unroll
        for (int r = 0; r < 4; ++r) {
            const int n = n0 + wave * 4 + r;
            Z[(size_t)n * S + lane] = za[r];
            Z[(size_t)n * S + 64 + lane] = zb[r];
            if (lane < 16) Z[(size_t)n * S + 128 + lane] = zc[r];
        }
    }
}

// ---------------- K_B: h = z.E + epilogue ----------------
// 512 blocks x 256 thr (4 waves), 8 rows/block, 2 rows/wave.
__global__ __launch_bounds__(256) void kB(const float* __restrict__ feat,
                                          const float* __restrict__ Zg,
                                          const float* __restrict__ Eg,
                                          float* __restrict__ out) {
    __shared__ float Esh[S * V];        // 72 KB
    __shared__ float zbuf[4][2][S];     // 4.5 KB
    const int tid = threadIdx.x;
    const int wave = tid >> 6;
    const int lane = tid & 63;
    const int n0 = blockIdx.x * 8 + wave * 2;

    // vector part of this wave's 2 rows -> regs (lane owns channels 2l, 2l+1)
    float2 va[2][3];
#pragma unroll
    for (int r = 0; r < 2; ++r) {
        const float* p = feat + (size_t)(n0 + r) * 512 + V + 6 * lane;
        va[r][0] = *(const float2*)(p + 0);
        va[r][1] = *(const float2*)(p + 2);
        va[r][2] = *(const float2*)(p + 4);
    }
    // z rows -> LDS (144 floats = 36 float4 per row)
#pragma unroll
    for (int r = 0; r < 2; ++r) {
        if (lane < 36) {
            const float4 zv = ((const float4*)(Zg + (size_t)(n0 + r) * S))[lane];
            *(float4*)&zbuf[wave][r][4 * lane] = zv;
        }
    }
    // cooperative E load: 18432 f32 = 4608 float4 / 256 thr
    {
        const float4* src = (const float4*)Eg;
        float4* dst = (float4*)Esh;
#pragma unroll
        for (int k = 0; k < 18; ++k)
            dst[tid + 256 * k] = src[tid + 256 * k];
    }
    __syncthreads();

    // h[r][c=2l,2l+1] = sum_u z[r][u] * E[u,c]
    float h0[2] = {0.f, 0.f};
    float h1[2] = {0.f, 0.f};
#pragma unroll 4
    for (int u = 0; u < S; ++u) {
        const float2 m2 = *(const float2*)&Esh[u * V + 2 * lane];
#pragma unroll
        for (int r = 0; r < 2; ++r) {
            const float zu = zbuf[wave][r][u];    // LDS broadcast
            h0[r] = fmaf(zu, m2.x, h0[r]);
            h1[r] = fmaf(zu, m2.y, h1[r]);
        }
    }

    // epilogue: lane l holds c=2l (va[0].x, va[0].y, va[1].x)
    // and c=2l+1 (va[1].y, va[2].x, va[2].y)
#pragma unroll
    for (int r = 0; r < 2; ++r) {
        float pm0 = va[r][0].x * h0[r] + va[r][1].y * h1[r];
        float pm1 = va[r][0].y * h0[r] + va[r][2].x * h1[r];
        float pm2 = va[r][1].x * h0[r] + va[r][2].y * h1[r];
#pragma unroll
        for (int off = 1; off < 64; off <<= 1) {
            pm0 += __shfl_xor(pm0, off, 64);
            pm1 += __shfl_xor(pm1, off, 64);
            pm2 += __shfl_xor(pm2, off, 64);
        }
        if (lane == 0) {
            out[(n0 + r) * 3 + 0] = pm0;
            out[(n0 + r) * 3 + 1] = pm1;
            out[(n0 + r) * 3 + 2] = pm2;
        }
    }
}

extern "C" void kernel_launch(void* const* d_in, const int* in_sizes, int n_in,
                              void* d_out, int out_size, void* d_ws, size_t ws_size,
                              hipStream_t stream) {
    const float* feat  = (const float*)d_in[0];  // [4096, 512]
    const float* times = (const float*)d_in[1];  // [4096, 1]
    const float* Wt    = (const float*)d_in[2];  // [1,16]
    const float* W1s   = (const float*)d_in[3];  // [144,144]
    const float* W1v   = (const float*)d_in[4];  // [128,128]
    // d_in[5] = Wss  -- dead path
    const float* Wsv   = (const float*)d_in[6];  // [144,128,128]
    // d_in[7] = Wvv  -- dead path
    const float* W2    = (const float*)d_in[8];  // [128,1]

    float* E = (float*)d_ws;          // 18432 f32
    float* Z = E + S * V;             // 4096*144 f32 (2.36 MB)

    kA<<<dim3(400), dim3(256), 0, stream>>>(feat, times, Wt, W1s, W1v, Wsv, W2, E, Z);
    kB<<<dim3(512), dim3(256), 0, stream>>>(feat, Z, E, (float*)d_out);
}